// Round 1
// baseline (430.516 us; speedup 1.0000x reference)
//
#include <hip/hip_runtime.h>
#include <hip/hip_bf16.h>

#define BB 2
#define CC 512
#define GG 32
#define NN 4096
#define EPSV 1e-6f

typedef __attribute__((ext_vector_type(4))) float f32x4;
typedef __attribute__((ext_vector_type(8))) short s16x8;
typedef __attribute__((ext_vector_type(4))) short s16x4;

__device__ __forceinline__ ushort f2bf(float f){
  union { float f; unsigned u; } v; v.f = f;
  unsigned r = v.u + 0x7fffu + ((v.u >> 16) & 1u);
  return (ushort)(r >> 16);
}
__device__ __forceinline__ short f2bfs(float f){ return (short)f2bf(f); }

__device__ __forceinline__ f32x4 mfma16(s16x8 a, s16x8 b, f32x4 c){
  return __builtin_amdgcn_mfma_f32_16x16x32_bf16(a, b, c, 0, 0, 0);
}

// ---------------- weight fp32 -> bf16 ----------------
__global__ __launch_bounds__(256) void k_convert_w(const float* __restrict__ wq, const float* __restrict__ wk,
                                                   const float* __restrict__ wv, const float* __restrict__ wp,
                                                   ushort* __restrict__ wbf){
  int idx = blockIdx.x * 256 + threadIdx.x;  // 65536 float4 per matrix
  const float* srcs[4] = {wq, wk, wv, wp};
  #pragma unroll
  for (int m = 0; m < 4; m++){
    float4 v = reinterpret_cast<const float4*>(srcs[m])[idx];
    ushort4 o; o.x = f2bf(v.x); o.y = f2bf(v.y); o.z = f2bf(v.z); o.w = f2bf(v.w);
    reinterpret_cast<ushort4*>(wbf + (size_t)m * CC * CC)[idx] = o;
  }
}

// ---------------- GroupNorm stats: one block per (b,g); group data is contiguous ----------------
__global__ __launch_bounds__(256) void k_gn_stats(const float* __restrict__ x, float* __restrict__ stats){
  int bg = blockIdx.x;  // 0..63
  const float* p = x + (size_t)bg * (16 * NN);
  float s = 0.f, ss = 0.f;
  for (int i = threadIdx.x; i < 16 * NN / 4; i += 256){
    float4 v = reinterpret_cast<const float4*>(p)[i];
    s  += v.x + v.y + v.z + v.w;
    ss += v.x*v.x + v.y*v.y + v.z*v.z + v.w*v.w;
  }
  #pragma unroll
  for (int off = 32; off; off >>= 1){ s += __shfl_down(s, off); ss += __shfl_down(ss, off); }
  __shared__ float rs_[4], rss_[4];
  int w = threadIdx.x >> 6, lane = threadIdx.x & 63;
  if (lane == 0){ rs_[w] = s; rss_[w] = ss; }
  __syncthreads();
  if (threadIdx.x == 0){
    float S = rs_[0] + rs_[1] + rs_[2] + rs_[3];
    float SS = rss_[0] + rss_[1] + rss_[2] + rss_[3];
    float inv = 1.0f / (16.0f * NN);
    float mean = S * inv;
    float var = SS * inv - mean * mean;
    stats[bg * 2 + 0] = mean;
    stats[bg * 2 + 1] = rsqrtf(var + EPSV);
  }
}

// ---------------- GN apply + transpose: x[b][c][n] -> hf_t[b][n][c] bf16 ----------------
__global__ __launch_bounds__(256) void k_gn_apply(const float* __restrict__ x, const float* __restrict__ gsc,
                                                  const float* __restrict__ gbi, const float* __restrict__ stats,
                                                  ushort* __restrict__ hf){
  __shared__ ushort tr[32][520];   // 520-elem rows: 1040B, 16B-aligned rows
  int b = blockIdx.y;
  int nb = blockIdx.x * 32;
  int t = threadIdx.x;
  int n = t & 31, cr = t >> 5;
  const float* xb = x + (size_t)b * CC * NN;
  for (int c0 = 0; c0 < CC; c0 += 8){
    int c = c0 + cr;
    float mean = stats[(b * GG + (c >> 4)) * 2 + 0];
    float rstd = stats[(b * GG + (c >> 4)) * 2 + 1];
    float v = xb[(size_t)c * NN + nb + n];
    tr[n][c] = f2bf((v - mean) * rstd * gsc[c] + gbi[c]);
  }
  __syncthreads();
  ushort* out = hf + ((size_t)b * NN + nb) * CC;
  int c8 = (t & 63) * 8;
  int nrow0 = t >> 6;
  #pragma unroll
  for (int i = 0; i < 8; i++){
    int nr = nrow0 + i * 4;
    *reinterpret_cast<s16x8*>(&out[(size_t)nr * CC + c8]) =
      *reinterpret_cast<const s16x8*>(&tr[nr][c8]);
  }
}

// ---------------- GEMM: out[o][n] = W[o][:] . Bt[n][:] + bias[o] ----------------
// MODE 0: bf16 out transposed [n][o] (for q,k). MODE 1: bf16 out [o][n] (for v).
// MODE 2: fp32 out [o][n] with residual add of xres (final proj).
template<int MODE>
__global__ __launch_bounds__(256) void k_gemm(const ushort* __restrict__ A, const ushort* __restrict__ Bt,
                                              const float* __restrict__ bias, ushort* __restrict__ o16,
                                              float* __restrict__ o32, const float* __restrict__ xres){
  __shared__ ushort Al[64][72];
  __shared__ ushort Bl[64][72];
  __shared__ float bl[64];
  __shared__ float trf[MODE == 2 ? 64 * 68 : 1];
  int b = blockIdx.z, ob = blockIdx.y * 64, nb = blockIdx.x * 64;
  int t = threadIdx.x, w = t >> 6, l = t & 63;
  int lr = l & 15, lk = l >> 4;
  int wo = (w >> 1) * 32, wn = (w & 1) * 32;
  if (t < 64) bl[t] = bias[ob + t];
  const ushort* Bp = Bt + ((size_t)b * NN + nb) * CC;
  const ushort* Ap = A + (size_t)ob * CC;
  int srow = t >> 2, scol = (t & 3) * 16;
  f32x4 acc[2][2] = {};
  for (int k0 = 0; k0 < CC; k0 += 64){
    *reinterpret_cast<s16x8*>(&Al[srow][scol])     = *reinterpret_cast<const s16x8*>(&Ap[(size_t)srow * CC + k0 + scol]);
    *reinterpret_cast<s16x8*>(&Al[srow][scol + 8]) = *reinterpret_cast<const s16x8*>(&Ap[(size_t)srow * CC + k0 + scol + 8]);
    *reinterpret_cast<s16x8*>(&Bl[srow][scol])     = *reinterpret_cast<const s16x8*>(&Bp[(size_t)srow * CC + k0 + scol]);
    *reinterpret_cast<s16x8*>(&Bl[srow][scol + 8]) = *reinterpret_cast<const s16x8*>(&Bp[(size_t)srow * CC + k0 + scol + 8]);
    __syncthreads();
    #pragma unroll
    for (int kk = 0; kk < 2; kk++){
      s16x8 a0 = *reinterpret_cast<const s16x8*>(&Al[wo + lr][kk * 32 + lk * 8]);
      s16x8 a1 = *reinterpret_cast<const s16x8*>(&Al[wo + 16 + lr][kk * 32 + lk * 8]);
      s16x8 b0 = *reinterpret_cast<const s16x8*>(&Bl[wn + lr][kk * 32 + lk * 8]);
      s16x8 b1 = *reinterpret_cast<const s16x8*>(&Bl[wn + 16 + lr][kk * 32 + lk * 8]);
      acc[0][0] = mfma16(a0, b0, acc[0][0]);
      acc[0][1] = mfma16(a0, b1, acc[0][1]);
      acc[1][0] = mfma16(a1, b0, acc[1][0]);
      acc[1][1] = mfma16(a1, b1, acc[1][1]);
    }
    __syncthreads();
  }
  if (MODE == 0){
    #pragma unroll
    for (int oi = 0; oi < 2; oi++)
      #pragma unroll
      for (int nj = 0; nj < 2; nj++){
        int o0 = wo + oi * 16 + lk * 4;
        int n  = nb + wn + nj * 16 + lr;
        s16x4 pv;
        #pragma unroll
        for (int r = 0; r < 4; r++) pv[r] = f2bfs(acc[oi][nj][r] + bl[o0 + r]);
        *reinterpret_cast<s16x4*>(&o16[((size_t)b * NN + n) * CC + ob + o0]) = pv;
      }
  } else if (MODE == 1){
    #pragma unroll
    for (int oi = 0; oi < 2; oi++)
      #pragma unroll
      for (int nj = 0; nj < 2; nj++){
        int o0 = wo + oi * 16 + lk * 4;
        int ncl = wn + nj * 16 + lr;
        #pragma unroll
        for (int r = 0; r < 4; r++) Al[o0 + r][ncl] = f2bf(acc[oi][nj][r] + bl[o0 + r]);
      }
    __syncthreads();
    {
      int o = t >> 2, ns = (t & 3) * 16;
      ushort* dst = &o16[((size_t)b * CC + ob + o) * NN + nb + ns];
      *reinterpret_cast<s16x8*>(dst)     = *reinterpret_cast<const s16x8*>(&Al[o][ns]);
      *reinterpret_cast<s16x8*>(dst + 8) = *reinterpret_cast<const s16x8*>(&Al[o][ns + 8]);
    }
  } else {
    #pragma unroll
    for (int oi = 0; oi < 2; oi++)
      #pragma unroll
      for (int nj = 0; nj < 2; nj++){
        int o0 = wo + oi * 16 + lk * 4;
        int ncl = wn + nj * 16 + lr;
        #pragma unroll
        for (int r = 0; r < 4; r++) trf[(o0 + r) * 68 + ncl] = acc[oi][nj][r] + bl[o0 + r];
      }
    __syncthreads();
    {
      int o = t >> 2, ns = (t & 3) * 16;
      size_t base = ((size_t)b * CC + ob + o) * NN + nb + ns;
      #pragma unroll
      for (int q = 0; q < 4; q++){
        float4 xv = *reinterpret_cast<const float4*>(&xres[base + q * 4]);
        float4 ov;
        ov.x = xv.x + trf[o * 68 + ns + q * 4 + 0];
        ov.y = xv.y + trf[o * 68 + ns + q * 4 + 1];
        ov.z = xv.z + trf[o * 68 + ns + q * 4 + 2];
        ov.w = xv.w + trf[o * 68 + ns + q * 4 + 3];
        *reinterpret_cast<float4*>(&o32[base + q * 4]) = ov;
      }
    }
  }
}

// ---------------- flash attention: BI=64 queries/block, BJ=32, 8 waves ----------------
// qt,kt: [b][n][c] bf16 ; v: [b][c][n] bf16 ; ot: [b][n][c] bf16
__global__ __launch_bounds__(512, 2) void k_attn(const ushort* __restrict__ qt, const ushort* __restrict__ kt,
                                                 const ushort* __restrict__ vv, ushort* __restrict__ ot){
  __shared__ ushort Kl[32 * 512];    // rows of 1024B, 16B-chunk XOR swizzle by (row&7)
  __shared__ float Sl[64][36];
  __shared__ ushort Pl[64 * 32];     // rows of 64B, 16B-chunk XOR swizzle by (row&3)
  __shared__ float ml[64], ll[64], cl[64];
  int b = blockIdx.y, ib = blockIdx.x * 64;
  int t = threadIdx.x, w = t >> 6, l = t & 63;
  int lr = l & 15, lk = l >> 4;
  int it4 = w >> 1, jt = w & 1;       // S-tile assignment: 4 i-tiles x 2 j-tiles
  const ushort* qb = qt + ((size_t)b * NN + ib) * CC;
  const ushort* kb = kt + (size_t)b * NN * CC;
  const ushort* vb = vv + (size_t)b * CC * NN;

  // Q fragments in registers (A-operand rows = i, k = c)
  s16x8 qf[16];
  #pragma unroll
  for (int k = 0; k < 16; k++)
    qf[k] = *reinterpret_cast<const s16x8*>(&qb[(size_t)(it4 * 16 + lr) * CC + k * 32 + lk * 8]);

  f32x4 oc[4][4] = {};  // [ct][it]: wave owns c-slice w*64..+64, all 64 i
  if (t < 64){ ml[t] = -1e30f; ll[t] = 0.f; }

  int krow = t >> 4, kcs = (t & 15) * 32;
  const float rs = 0.044194173824159216f;  // 512^-0.5

  for (int j0 = 0; j0 < NN; j0 += 32){
    // stage K rows j0..j0+32 (swizzled)
    {
      const ushort* src = &kb[(size_t)(j0 + krow) * CC + kcs];
      #pragma unroll
      for (int q = 0; q < 4; q++){
        int chunk = (kcs >> 3) + q;
        int sw = chunk ^ (krow & 7);
        *reinterpret_cast<s16x8*>(&Kl[krow * 512 + sw * 8]) = *reinterpret_cast<const s16x8*>(&src[q * 8]);
      }
    }
    // V fragments straight from global (each element used by exactly one wave)
    s16x8 vf[4];
    #pragma unroll
    for (int ct = 0; ct < 4; ct++)
      vf[ct] = *reinterpret_cast<const s16x8*>(&vb[(size_t)(w * 64 + ct * 16 + lr) * NN + j0 + lk * 8]);
    __syncthreads();
    // S tile (16i x 16j) per wave
    f32x4 s = {0.f, 0.f, 0.f, 0.f};
    #pragma unroll
    for (int k = 0; k < 16; k++){
      int row = jt * 16 + lr;
      int chunk = (k * 4 + lk) ^ (row & 7);
      s16x8 kf = *reinterpret_cast<const s16x8*>(&Kl[row * 512 + chunk * 8]);
      s = mfma16(qf[k], kf, s);
    }
    #pragma unroll
    for (int r = 0; r < 4; r++)
      Sl[it4 * 16 + lk * 4 + r][jt * 16 + lr] = s[r] * rs;
    __syncthreads();
    // online softmax: 8 lanes per row
    {
      int row = t >> 3, seg = t & 7;
      f32x4 sv = *reinterpret_cast<const f32x4*>(&Sl[row][seg * 4]);
      float mloc = fmaxf(fmaxf(sv[0], sv[1]), fmaxf(sv[2], sv[3]));
      #pragma unroll
      for (int off = 1; off < 8; off <<= 1) mloc = fmaxf(mloc, __shfl_xor(mloc, off));
      float mold = ml[row];
      float mnew = fmaxf(mold, mloc);
      float p0 = __expf(sv[0] - mnew), p1 = __expf(sv[1] - mnew);
      float p2 = __expf(sv[2] - mnew), p3 = __expf(sv[3] - mnew);
      float lsum = p0 + p1 + p2 + p3;
      #pragma unroll
      for (int off = 1; off < 8; off <<= 1) lsum += __shfl_xor(lsum, off);
      float corr = __expf(mold - mnew);
      if (seg == 0){ ml[row] = mnew; ll[row] = ll[row] * corr + lsum; cl[row] = corr; }
      s16x4 pb; pb[0] = f2bfs(p0); pb[1] = f2bfs(p1); pb[2] = f2bfs(p2); pb[3] = f2bfs(p3);
      char* pd = reinterpret_cast<char*>(Pl) + row * 64 + ((((seg >> 1) ^ (row & 3)) << 4) | ((seg & 1) << 3));
      *reinterpret_cast<s16x4*>(pd) = pb;
    }
    __syncthreads();
    // rescale O by corr (per output column i), then O += V.P^T
    #pragma unroll
    for (int itt = 0; itt < 4; itt++){
      float corr = cl[itt * 16 + lr];
      #pragma unroll
      for (int ct = 0; ct < 4; ct++){
        oc[ct][itt][0] *= corr; oc[ct][itt][1] *= corr;
        oc[ct][itt][2] *= corr; oc[ct][itt][3] *= corr;
      }
    }
    #pragma unroll
    for (int itt = 0; itt < 4; itt++){
      int prow = itt * 16 + lr;
      const char* ps = reinterpret_cast<const char*>(Pl) + prow * 64 + ((lk ^ (prow & 3)) << 4);
      s16x8 pf = *reinterpret_cast<const s16x8*>(ps);
      #pragma unroll
      for (int ct = 0; ct < 4; ct++)
        oc[ct][itt] = mfma16(vf[ct], pf, oc[ct][itt]);
    }
    __syncthreads();
  }
  // epilogue: divide by softmax denom, write ot[b][n][c]
  #pragma unroll
  for (int itt = 0; itt < 4; itt++){
    float linv = 1.0f / ll[itt * 16 + lr];
    #pragma unroll
    for (int ct = 0; ct < 4; ct++){
      s16x4 ov;
      #pragma unroll
      for (int r = 0; r < 4; r++) ov[r] = f2bfs(oc[ct][itt][r] * linv);
      *reinterpret_cast<s16x4*>(&ot[((size_t)b * NN + ib + itt * 16 + lr) * CC + w * 64 + ct * 16 + lk * 4]) = ov;
    }
  }
}

extern "C" void kernel_launch(void* const* d_in, const int* in_sizes, int n_in,
                              void* d_out, int out_size, void* d_ws, size_t ws_size,
                              hipStream_t stream){
  const float* x   = (const float*)d_in[0];
  const float* gsc = (const float*)d_in[1];
  const float* gbi = (const float*)d_in[2];
  const float* wq  = (const float*)d_in[3];
  const float* bq  = (const float*)d_in[4];
  const float* wk  = (const float*)d_in[5];
  const float* bk  = (const float*)d_in[6];
  const float* wv  = (const float*)d_in[7];
  const float* bv  = (const float*)d_in[8];
  const float* wp  = (const float*)d_in[9];
  const float* bp  = (const float*)d_in[10];
  char* ws = (char*)d_ws;
  // workspace map (34MB + 512B):
  ushort* wbf = (ushort*)ws;                                  // 2 MB: [q|k|v|proj] bf16 weights
  ushort* qtb = (ushort*)(ws + (size_t)2  * 1024 * 1024);     // 8 MB: q^T [b][n][c]
  ushort* ktb = (ushort*)(ws + (size_t)10 * 1024 * 1024);     // 8 MB: k^T [b][n][c]
  ushort* vvb = (ushort*)(ws + (size_t)18 * 1024 * 1024);     // 8 MB: v   [b][c][n]
  ushort* hfb = (ushort*)(ws + (size_t)26 * 1024 * 1024);     // 8 MB: hf^T [b][n][c] (reused as attn-out)
  float* stats = (float*)(ws + (size_t)34 * 1024 * 1024);     // 512 B
  ushort* otb = hfb;  // hf dead after QKV; attention output aliases it

  k_convert_w<<<256, 256, 0, stream>>>(wq, wk, wv, wp, wbf);
  k_gn_stats<<<64, 256, 0, stream>>>(x, stats);
  k_gn_apply<<<dim3(128, 2, 1), 256, 0, stream>>>(x, gsc, gbi, stats, hfb);
  k_gemm<0><<<dim3(64, 8, 2), 256, 0, stream>>>(wbf,               hfb, bq, qtb, nullptr, nullptr);
  k_gemm<0><<<dim3(64, 8, 2), 256, 0, stream>>>(wbf + CC * CC,     hfb, bk, ktb, nullptr, nullptr);
  k_gemm<1><<<dim3(64, 8, 2), 256, 0, stream>>>(wbf + 2 * CC * CC, hfb, bv, vvb, nullptr, nullptr);
  k_attn<<<dim3(64, 2, 1), 512, 0, stream>>>(qtb, ktb, vvb, otb);
  k_gemm<2><<<dim3(64, 8, 2), 256, 0, stream>>>(wbf + 3 * CC * CC, otb, bp, nullptr, (float*)d_out, x);
}

// Round 2
// 258.570 us; speedup vs baseline: 1.6650x; 1.6650x over previous
//
#include <hip/hip_runtime.h>
#include <hip/hip_bf16.h>

#define BB 2
#define CC 512
#define GG 32
#define NN 4096
#define EPSV 1e-6f

typedef __attribute__((ext_vector_type(4))) float f32x4;
typedef __attribute__((ext_vector_type(8))) short s16x8;
typedef __attribute__((ext_vector_type(4))) short s16x4;

__device__ __forceinline__ ushort f2bf(float f){
  union { float f; unsigned u; } v; v.f = f;
  unsigned r = v.u + 0x7fffu + ((v.u >> 16) & 1u);
  return (ushort)(r >> 16);
}
__device__ __forceinline__ short f2bfs(float f){ return (short)f2bf(f); }

__device__ __forceinline__ f32x4 mfma16(s16x8 a, s16x8 b, f32x4 c){
  return __builtin_amdgcn_mfma_f32_16x16x32_bf16(a, b, c, 0, 0, 0);
}

#define GLOAD_LDS16(g, l) __builtin_amdgcn_global_load_lds( \
    (const __attribute__((address_space(1))) void*)(g),     \
    (__attribute__((address_space(3))) void*)(l), 16, 0, 0)

// ---------------- weight fp32 -> bf16 ----------------
__global__ __launch_bounds__(256) void k_convert_w(const float* __restrict__ wq, const float* __restrict__ wk,
                                                   const float* __restrict__ wv, const float* __restrict__ wp,
                                                   ushort* __restrict__ wbf){
  int idx = blockIdx.x * 256 + threadIdx.x;
  const float* srcs[4] = {wq, wk, wv, wp};
  #pragma unroll
  for (int m = 0; m < 4; m++){
    float4 v = reinterpret_cast<const float4*>(srcs[m])[idx];
    ushort4 o; o.x = f2bf(v.x); o.y = f2bf(v.y); o.z = f2bf(v.z); o.w = f2bf(v.w);
    reinterpret_cast<ushort4*>(wbf + (size_t)m * CC * CC)[idx] = o;
  }
}

// ---------------- GroupNorm stats ----------------
__global__ __launch_bounds__(256) void k_gn_stats(const float* __restrict__ x, float* __restrict__ stats){
  int bg = blockIdx.x;  // 0..63
  const float* p = x + (size_t)bg * (16 * NN);
  float s = 0.f, ss = 0.f;
  for (int i = threadIdx.x; i < 16 * NN / 4; i += 256){
    float4 v = reinterpret_cast<const float4*>(p)[i];
    s  += v.x + v.y + v.z + v.w;
    ss += v.x*v.x + v.y*v.y + v.z*v.z + v.w*v.w;
  }
  #pragma unroll
  for (int off = 32; off; off >>= 1){ s += __shfl_down(s, off); ss += __shfl_down(ss, off); }
  __shared__ float rs_[4], rss_[4];
  int w = threadIdx.x >> 6, lane = threadIdx.x & 63;
  if (lane == 0){ rs_[w] = s; rss_[w] = ss; }
  __syncthreads();
  if (threadIdx.x == 0){
    float S = rs_[0] + rs_[1] + rs_[2] + rs_[3];
    float SS = rss_[0] + rss_[1] + rss_[2] + rss_[3];
    float inv = 1.0f / (16.0f * NN);
    float mean = S * inv;
    float var = SS * inv - mean * mean;
    stats[bg * 2 + 0] = mean;
    stats[bg * 2 + 1] = rsqrtf(var + EPSV);
  }
}

// ---------------- GN apply + transpose: x[b][c][n] -> hf_t[b][n][c] bf16 ----------------
__global__ __launch_bounds__(256) void k_gn_apply(const float* __restrict__ x, const float* __restrict__ gsc,
                                                  const float* __restrict__ gbi, const float* __restrict__ stats,
                                                  ushort* __restrict__ hf){
  __shared__ ushort tr[32][520];
  int b = blockIdx.y;
  int nb = blockIdx.x * 32;
  int t = threadIdx.x;
  int n = t & 31, cr = t >> 5;
  const float* xb = x + (size_t)b * CC * NN;
  for (int c0 = 0; c0 < CC; c0 += 8){
    int c = c0 + cr;
    float mean = stats[(b * GG + (c >> 4)) * 2 + 0];
    float rstd = stats[(b * GG + (c >> 4)) * 2 + 1];
    float v = xb[(size_t)c * NN + nb + n];
    tr[n][c] = f2bf((v - mean) * rstd * gsc[c] + gbi[c]);
  }
  __syncthreads();
  ushort* out = hf + ((size_t)b * NN + nb) * CC;
  int c8 = (t & 63) * 8;
  int nrow0 = t >> 6;
  #pragma unroll
  for (int i = 0; i < 8; i++){
    int nr = nrow0 + i * 4;
    *reinterpret_cast<s16x8*>(&out[(size_t)nr * CC + c8]) =
      *reinterpret_cast<const s16x8*>(&tr[nr][c8]);
  }
}

// ---------------- GEMM: out[o][n] = W[o][:] . Bt[n][:] + bias[o] ----------------
// MODE 0: bf16 out transposed [n][o], scaled by scl. MODE 1: bf16 out [o][n].
// MODE 2: fp32 out [o][n] + residual.
template<int MODE>
__global__ __launch_bounds__(256) void k_gemm(const ushort* __restrict__ A, const ushort* __restrict__ Bt,
                                              const float* __restrict__ bias, ushort* __restrict__ o16,
                                              float* __restrict__ o32, const float* __restrict__ xres,
                                              float scl){
  __shared__ ushort Al[64][72];
  __shared__ ushort Bl[64][72];
  __shared__ float bl[64];
  __shared__ float trf[MODE == 2 ? 64 * 68 : 1];
  int b = blockIdx.z, ob = blockIdx.y * 64, nb = blockIdx.x * 64;
  int t = threadIdx.x, w = t >> 6, l = t & 63;
  int lr = l & 15, lk = l >> 4;
  int wo = (w >> 1) * 32, wn = (w & 1) * 32;
  if (t < 64) bl[t] = bias[ob + t];
  const ushort* Bp = Bt + ((size_t)b * NN + nb) * CC;
  const ushort* Ap = A + (size_t)ob * CC;
  int srow = t >> 2, scol = (t & 3) * 16;
  f32x4 acc[2][2] = {};
  for (int k0 = 0; k0 < CC; k0 += 64){
    *reinterpret_cast<s16x8*>(&Al[srow][scol])     = *reinterpret_cast<const s16x8*>(&Ap[(size_t)srow * CC + k0 + scol]);
    *reinterpret_cast<s16x8*>(&Al[srow][scol + 8]) = *reinterpret_cast<const s16x8*>(&Ap[(size_t)srow * CC + k0 + scol + 8]);
    *reinterpret_cast<s16x8*>(&Bl[srow][scol])     = *reinterpret_cast<const s16x8*>(&Bp[(size_t)srow * CC + k0 + scol]);
    *reinterpret_cast<s16x8*>(&Bl[srow][scol + 8]) = *reinterpret_cast<const s16x8*>(&Bp[(size_t)srow * CC + k0 + scol + 8]);
    __syncthreads();
    #pragma unroll
    for (int kk = 0; kk < 2; kk++){
      s16x8 a0 = *reinterpret_cast<const s16x8*>(&Al[wo + lr][kk * 32 + lk * 8]);
      s16x8 a1 = *reinterpret_cast<const s16x8*>(&Al[wo + 16 + lr][kk * 32 + lk * 8]);
      s16x8 b0 = *reinterpret_cast<const s16x8*>(&Bl[wn + lr][kk * 32 + lk * 8]);
      s16x8 b1 = *reinterpret_cast<const s16x8*>(&Bl[wn + 16 + lr][kk * 32 + lk * 8]);
      acc[0][0] = mfma16(a0, b0, acc[0][0]);
      acc[0][1] = mfma16(a0, b1, acc[0][1]);
      acc[1][0] = mfma16(a1, b0, acc[1][0]);
      acc[1][1] = mfma16(a1, b1, acc[1][1]);
    }
    __syncthreads();
  }
  if (MODE == 0){
    #pragma unroll
    for (int oi = 0; oi < 2; oi++)
      #pragma unroll
      for (int nj = 0; nj < 2; nj++){
        int o0 = wo + oi * 16 + lk * 4;
        int n  = nb + wn + nj * 16 + lr;
        s16x4 pv;
        #pragma unroll
        for (int r = 0; r < 4; r++) pv[r] = f2bfs((acc[oi][nj][r] + bl[o0 + r]) * scl);
        *reinterpret_cast<s16x4*>(&o16[((size_t)b * NN + n) * CC + ob + o0]) = pv;
      }
  } else if (MODE == 1){
    #pragma unroll
    for (int oi = 0; oi < 2; oi++)
      #pragma unroll
      for (int nj = 0; nj < 2; nj++){
        int o0 = wo + oi * 16 + lk * 4;
        int ncl = wn + nj * 16 + lr;
        #pragma unroll
        for (int r = 0; r < 4; r++) Al[o0 + r][ncl] = f2bf(acc[oi][nj][r] + bl[o0 + r]);
      }
    __syncthreads();
    {
      int o = t >> 2, ns = (t & 3) * 16;
      ushort* dst = &o16[((size_t)b * CC + ob + o) * NN + nb + ns];
      *reinterpret_cast<s16x8*>(dst)     = *reinterpret_cast<const s16x8*>(&Al[o][ns]);
      *reinterpret_cast<s16x8*>(dst + 8) = *reinterpret_cast<const s16x8*>(&Al[o][ns + 8]);
    }
  } else {
    #pragma unroll
    for (int oi = 0; oi < 2; oi++)
      #pragma unroll
      for (int nj = 0; nj < 2; nj++){
        int o0 = wo + oi * 16 + lk * 4;
        int ncl = wn + nj * 16 + lr;
        #pragma unroll
        for (int r = 0; r < 4; r++) trf[(o0 + r) * 68 + ncl] = acc[oi][nj][r] + bl[o0 + r];
      }
    __syncthreads();
    {
      int o = t >> 2, ns = (t & 3) * 16;
      size_t base = ((size_t)b * CC + ob + o) * NN + nb + ns;
      #pragma unroll
      for (int q = 0; q < 4; q++){
        float4 xv = *reinterpret_cast<const float4*>(&xres[base + q * 4]);
        float4 ov;
        ov.x = xv.x + trf[o * 68 + ns + q * 4 + 0];
        ov.y = xv.y + trf[o * 68 + ns + q * 4 + 1];
        ov.z = xv.z + trf[o * 68 + ns + q * 4 + 2];
        ov.w = xv.w + trf[o * 68 + ns + q * 4 + 3];
        *reinterpret_cast<float4*>(&o32[base + q * 4]) = ov;
      }
    }
  }
}

// ---------------- flash attention v2 ----------------
// qt,kt: [b][n][c] bf16 (q pre-scaled by c^-0.5); v: [b][c][n] bf16.
// Block: 256 thr (4 waves), BI=64 (wave w owns i-tile w for S + softmax),
// PV c-split: wave w owns channels w*128..+128 for ALL 64 i.
// K tile BJ=32 double-buffered in LDS via global_load_lds, XOR-swizzled source.
// grid: (N/64, nsplit, B). nsplit>1 -> write unnormalized partials + m,l.
__global__ __launch_bounds__(256, 2) void k_attn2(const ushort* __restrict__ qt, const ushort* __restrict__ kt,
                                                  const ushort* __restrict__ vv, ushort* __restrict__ ot,
                                                  float* __restrict__ opart, float* __restrict__ mpart,
                                                  float* __restrict__ lpart, int nsplit){
  __shared__ ushort Kl[2][32][512];   // rows 1KB; LDS[j][x] holds K[j][x ^ (j&7)] (16B chunks)
  __shared__ ushort Pl[64][40];       // P[i][j], row padded to 80B -> 2-way-only conflicts
  __shared__ float cl[64], llds[64];
  int b = blockIdx.z, s = blockIdx.y, ib = blockIdx.x * 64;
  int t = threadIdx.x, w = t >> 6, l = t & 63;
  int lr = l & 15, lk = l >> 4;
  int jlen = NN / nsplit;
  int jbase = s * jlen;
  int niter = jlen / 32;
  const ushort* qb = qt + ((size_t)b * NN + ib) * CC;
  const ushort* kb = kt + (size_t)b * NN * CC;
  const ushort* vb = vv + (size_t)b * CC * NN;

  // Q B-fragments for this wave's i-tile (col i = w*16+lr, k els = c)
  s16x8 qf[16];
  #pragma unroll
  for (int k = 0; k < 16; k++)
    qf[k] = *reinterpret_cast<const s16x8*>(&qb[(size_t)(w * 16 + lr) * CC + k * 32 + lk * 8]);

  f32x4 oc[8][4] = {};   // [ct][it]: O[c = w*128+ct*16+lk*4+r][i = it*16+lr]
  float m_run = -1e30f, l_run = 0.f;

  // prologue: stage K rows jbase..+31 into buf0
  #pragma unroll
  for (int q = 0; q < 8; q++){
    int j = q * 4 + w;
    const ushort* src = kb + (size_t)(jbase + j) * CC + ((l ^ (j & 7)) << 3);
    GLOAD_LDS16(src, &Kl[0][j][0]);
  }
  __syncthreads();
  int cur = 0;
  for (int it = 0; it < niter; it++){
    int j0 = jbase + it * 32;
    if (it + 1 < niter){
      #pragma unroll
      for (int q = 0; q < 8; q++){
        int j = q * 4 + w;
        const ushort* src = kb + (size_t)(j0 + 32 + j) * CC + ((l ^ (j & 7)) << 3);
        GLOAD_LDS16(src, &Kl[cur ^ 1][j][0]);
      }
    }
    // S^T = K.Q for own i-tile: rows j (A=K), cols i (B=Q)
    f32x4 sa = {0.f,0.f,0.f,0.f}, sb = {0.f,0.f,0.f,0.f};
    #pragma unroll
    for (int k = 0; k < 16; k++){
      int x = ((k * 4 + lk) ^ (lr & 7)) << 3;
      s16x8 k0 = *reinterpret_cast<const s16x8*>(&Kl[cur][lr][x]);
      s16x8 k1 = *reinterpret_cast<const s16x8*>(&Kl[cur][16 + lr][x]);
      sa = mfma16(k0, qf[k], sa);
      sb = mfma16(k1, qf[k], sb);
    }
    // in-register online softmax (lane has 8 j-values for i = w*16+lr)
    float mx = fmaxf(fmaxf(fmaxf(sa[0], sa[1]), fmaxf(sa[2], sa[3])),
                     fmaxf(fmaxf(sb[0], sb[1]), fmaxf(sb[2], sb[3])));
    mx = fmaxf(mx, __shfl_xor(mx, 16));
    mx = fmaxf(mx, __shfl_xor(mx, 32));
    float mnew = fmaxf(m_run, mx);
    float corr = __expf(m_run - mnew);
    float p[8];
    p[0] = __expf(sa[0] - mnew); p[1] = __expf(sa[1] - mnew);
    p[2] = __expf(sa[2] - mnew); p[3] = __expf(sa[3] - mnew);
    p[4] = __expf(sb[0] - mnew); p[5] = __expf(sb[1] - mnew);
    p[6] = __expf(sb[2] - mnew); p[7] = __expf(sb[3] - mnew);
    float ls = (p[0] + p[1]) + (p[2] + p[3]) + (p[4] + p[5]) + (p[6] + p[7]);
    ls += __shfl_xor(ls, 16);
    ls += __shfl_xor(ls, 32);
    l_run = l_run * corr + ls;
    m_run = mnew;
    // write P tile: rows i = w*16+lr, j = js*16 + lk*4 + r
    s16x4 pA, pB;
    #pragma unroll
    for (int r = 0; r < 4; r++){ pA[r] = f2bfs(p[r]); pB[r] = f2bfs(p[4 + r]); }
    *reinterpret_cast<s16x4*>(&Pl[w * 16 + lr][lk * 4])      = pA;
    *reinterpret_cast<s16x4*>(&Pl[w * 16 + lr][16 + lk * 4]) = pB;
    if (lk == 0) cl[w * 16 + lr] = corr;
    __syncthreads();
    // rescale O, then PV: O[c][i] += sum_j V[c][j] P[i][j]
    float cr0 = cl[lr], cr1 = cl[16 + lr], cr2 = cl[32 + lr], cr3 = cl[48 + lr];
    #pragma unroll
    for (int ct = 0; ct < 8; ct++){
      #pragma unroll
      for (int r = 0; r < 4; r++){
        oc[ct][0][r] *= cr0; oc[ct][1][r] *= cr1;
        oc[ct][2][r] *= cr2; oc[ct][3][r] *= cr3;
      }
    }
    s16x8 pf[4];
    #pragma unroll
    for (int it4 = 0; it4 < 4; it4++)
      pf[it4] = *reinterpret_cast<const s16x8*>(&Pl[it4 * 16 + lr][lk * 8]);
    #pragma unroll
    for (int ct = 0; ct < 8; ct++){
      s16x8 vf = *reinterpret_cast<const s16x8*>(&vb[(size_t)(w * 128 + ct * 16 + lr) * NN + j0 + lk * 8]);
      #pragma unroll
      for (int it4 = 0; it4 < 4; it4++)
        oc[ct][it4] = mfma16(vf, pf[it4], oc[ct][it4]);
    }
    __syncthreads();
    cur ^= 1;
  }
  if (lk == 0) llds[w * 16 + lr] = l_run;
  __syncthreads();
  if (nsplit == 1){
    #pragma unroll
    for (int it4 = 0; it4 < 4; it4++){
      float linv = 1.0f / llds[it4 * 16 + lr];
      #pragma unroll
      for (int ct = 0; ct < 8; ct++){
        s16x4 ov;
        #pragma unroll
        for (int r = 0; r < 4; r++) ov[r] = f2bfs(oc[ct][it4][r] * linv);
        *reinterpret_cast<s16x4*>(&ot[((size_t)b * NN + ib + it4 * 16 + lr) * CC + w * 128 + ct * 16 + lk * 4]) = ov;
      }
    }
  } else {
    #pragma unroll
    for (int it4 = 0; it4 < 4; it4++){
      size_t nrow = (size_t)(s * BB + b) * NN + ib + it4 * 16 + lr;
      #pragma unroll
      for (int ct = 0; ct < 8; ct++){
        f32x4 ov = oc[ct][it4];
        *reinterpret_cast<f32x4*>(&opart[nrow * CC + w * 128 + ct * 16 + lk * 4]) = ov;
      }
    }
    if (w == (t >> 6) && lk == 0){
      mpart[(size_t)(s * BB + b) * NN + ib + w * 16 + lr] = m_run;
      lpart[(size_t)(s * BB + b) * NN + ib + w * 16 + lr] = l_run;
    }
  }
}

// ---------------- combine j-split partials ----------------
__global__ __launch_bounds__(128) void k_combine(const float* __restrict__ opart, const float* __restrict__ mpart,
                                                 const float* __restrict__ lpart, ushort* __restrict__ ot, int S){
  int n = blockIdx.x, b = blockIdx.y;
  float M = -1e30f;
  for (int s = 0; s < S; s++) M = fmaxf(M, mpart[(size_t)(s * BB + b) * NN + n]);
  float L = 0.f;
  for (int s = 0; s < S; s++)
    L += lpart[(size_t)(s * BB + b) * NN + n] * __expf(mpart[(size_t)(s * BB + b) * NN + n] - M);
  float linv = 1.0f / L;
  int c = threadIdx.x * 4;
  f32x4 acc = {0.f, 0.f, 0.f, 0.f};
  for (int s = 0; s < S; s++){
    float wgt = __expf(mpart[(size_t)(s * BB + b) * NN + n] - M);
    f32x4 v = *reinterpret_cast<const f32x4*>(&opart[((size_t)(s * BB + b) * NN + n) * CC + c]);
    acc[0] += v[0] * wgt; acc[1] += v[1] * wgt; acc[2] += v[2] * wgt; acc[3] += v[3] * wgt;
  }
  s16x4 ov;
  #pragma unroll
  for (int r = 0; r < 4; r++) ov[r] = f2bfs(acc[r] * linv);
  *reinterpret_cast<s16x4*>(&ot[((size_t)b * NN + n) * CC + c]) = ov;
}

extern "C" void kernel_launch(void* const* d_in, const int* in_sizes, int n_in,
                              void* d_out, int out_size, void* d_ws, size_t ws_size,
                              hipStream_t stream){
  const float* x   = (const float*)d_in[0];
  const float* gsc = (const float*)d_in[1];
  const float* gbi = (const float*)d_in[2];
  const float* wq  = (const float*)d_in[3];
  const float* bq  = (const float*)d_in[4];
  const float* wk  = (const float*)d_in[5];
  const float* bk  = (const float*)d_in[6];
  const float* wv  = (const float*)d_in[7];
  const float* bv  = (const float*)d_in[8];
  const float* wp  = (const float*)d_in[9];
  const float* bp  = (const float*)d_in[10];
  char* ws = (char*)d_ws;
  const size_t MB = 1024 * 1024;
  ushort* wbf = (ushort*)ws;                       // 2 MB
  ushort* qtb = (ushort*)(ws + 2 * MB);            // 8 MB: q^T [b][n][c] (pre-scaled)
  ushort* ktb = (ushort*)(ws + 10 * MB);           // 8 MB: k^T [b][n][c]
  ushort* vvb = (ushort*)(ws + 18 * MB);           // 8 MB: v   [b][c][n]
  ushort* hfb = (ushort*)(ws + 26 * MB);           // 8 MB: hf^T / attn-out [b][n][c]
  float* stats = (float*)(ws + 34 * MB);           // 512 B
  float* mpart = (float*)(ws + 34 * MB + 4096);    // <=128 KB
  float* lpart = (float*)(ws + 34 * MB + 300 * 1024);
  float* opart = (float*)(ws + 35 * MB);           // S*16 MB
  ushort* otb = hfb;

  int S = (ws_size >= 99 * MB) ? 4 : (ws_size >= 67 * MB) ? 2 : 1;
  const float rs = 0.044194173824159216f;  // 512^-0.5

  k_convert_w<<<256, 256, 0, stream>>>(wq, wk, wv, wp, wbf);
  k_gn_stats<<<64, 256, 0, stream>>>(x, stats);
  k_gn_apply<<<dim3(128, 2, 1), 256, 0, stream>>>(x, gsc, gbi, stats, hfb);
  k_gemm<0><<<dim3(64, 8, 2), 256, 0, stream>>>(wbf,               hfb, bq, qtb, nullptr, nullptr, rs);
  k_gemm<0><<<dim3(64, 8, 2), 256, 0, stream>>>(wbf + CC * CC,     hfb, bk, ktb, nullptr, nullptr, 1.0f);
  k_gemm<1><<<dim3(64, 8, 2), 256, 0, stream>>>(wbf + 2 * CC * CC, hfb, bv, vvb, nullptr, nullptr, 1.0f);
  k_attn2<<<dim3(64, S, 2), 256, 0, stream>>>(qtb, ktb, vvb, otb, opart, mpart, lpart, S);
  if (S > 1)
    k_combine<<<dim3(NN, 2, 1), 128, 0, stream>>>(opart, mpart, lpart, otb, S);
  k_gemm<2><<<dim3(64, 8, 2), 256, 0, stream>>>(wbf + 3 * CC * CC, otb, bp, nullptr, (float*)d_out, x, 1.0f);
}